// Round 5
// baseline (300.288 us; speedup 1.0000x reference)
//
#include <hip/hip_runtime.h>
#include <hip/hip_bf16.h>
#include <cstdint>

// Problem: B=256, N0=64, D0=128, N1=64, D1=128 (all fp32 in/out).
// u[b,n1,n0,d1] = sum_d0 x[b,n0,d0]*W[n1,n0,d0,d1]
// s = sum_n0 u ; logit = (u . s)/sqrt(128) ; c = softmax_n1(logit) + bias
// out[b,n1,d1] = sum_n0 u*c
//
// ws layout: u bf16 [B][N1][N0][D1]      @ 0          (268435456 B)
//            logits f32 [B][N1][N0]      @ 268435456  (4194304 B)
//            cc/xbf shared region        @ 272629760  (4194304 B)

#define BB 256
#define NN0 64
#define DD0 128
#define NN1 64
#define DD1 128

typedef __attribute__((ext_vector_type(8))) short bf16x8;
typedef __attribute__((ext_vector_type(4))) float f32x4;

__device__ __forceinline__ ushort f2bf(float f) {
  uint32_t b = __float_as_uint(f);
  b += 0x7FFFu + ((b >> 16) & 1u);      // RNE
  return (ushort)(b >> 16);
}
__device__ __forceinline__ float bf2f(ushort h) {
  return __uint_as_float(((uint32_t)h) << 16);
}

__device__ __forceinline__ void gld_lds16(const void* g, void* l) {
  __builtin_amdgcn_global_load_lds(
      (const __attribute__((address_space(1))) void*)g,
      (__attribute__((address_space(3))) void*)l, 16, 0, 0);
}

// barrier that does NOT drain vmcnt (keeps W prefetch in flight across it).
// lgkmcnt(0) before arrival makes this wave's LDS writes visible to all.
__device__ __forceinline__ void bar_lgkm() {
  asm volatile("s_waitcnt lgkmcnt(0)" ::: "memory");
  __builtin_amdgcn_s_barrier();
  __builtin_amdgcn_sched_barrier(0);
}

// ---------------- Px: x fp32 -> bf16
__global__ __launch_bounds__(512) void px_cvt(
    const float* __restrict__ x, ushort* __restrict__ xbf)
{
  int i = blockIdx.x * 512 + threadIdx.x;   // 524288 float4 chunks total
  float4 v = *reinterpret_cast<const float4*>(x + (size_t)i * 4);
  ushort4 h;
  h.x = f2bf(v.x); h.y = f2bf(v.y); h.z = f2bf(v.z); h.w = f2bf(v.w);
  *reinterpret_cast<ushort4*>(xbf + (size_t)i * 4) = h;
}

// ---------------- K1: block = (n0, group of 8 n1). A = x[:,n0,:] (256b x 128k)
// staged ONCE via global_load_lds (64KB). W streamed as 16 K-steps (8 n1 x 2
// k-halves) through reg-dbuf (hhA/hhB) -> B-LDS dbuf. Raw barriers with
// lgkmcnt(0) only: W loads stay in flight across barriers (T3/T4).
// LDS: A 64K | B0 16K | B1 16K | Epi 16K = 112KB -> 1 block/CU, 8 waves.
// launch_bounds(512,2): LDS caps blocks/CU at 1, so VGPR budget is 256/wave —
// do NOT request more waves (R2: a tight VGPR cap spilled acc -> 5x slower).
__global__ __launch_bounds__(512, 2) void k1_gemm(
    const ushort* __restrict__ xbf, const float* __restrict__ W,
    ushort* __restrict__ u)
{
  __shared__ __align__(16) char lds[114688];
  char* Alds = lds;                         // 256 rows(b) x 256B (k=128), XOR-swz
  char* Bl0  = lds + 65536;                 // 128 rows(d1) x 128B (k-half), XOR-swz
  char* Bl1  = lds + 81920;
  char* Epi  = lds + 98304;                 // 64 rows x 256B

  // XCD-chunk: XCD x gets blocks with n0 in [x*8, x*8+8) (8 g-blocks share
  // each n0 -> x slice L2-resident); grid 512 = 2 rounds at 1 block/CU.
  const int q = blockIdx.x;
  const int n0g = (q & 7) * 64 + (q >> 3);
  const int n0 = n0g >> 3, g = n0g & 7;
  const int n1base = g * 8;
  const int t = threadIdx.x;
  const int lane = t & 63, wave = t >> 6;
  const int wm = wave >> 1, wn = wave & 1;  // 4 M-waves(64b) x 2 N-waves(64 d1)

  const ushort* xb = xbf + n0 * DD0;        // + b*8192 + d0
  ushort* ubase = u + (size_t)n0 * 128;     // + b*524288 + n1*8192 + d1

  f32x4 acc[4][4];
#pragma unroll
  for (int a = 0; a < 4; ++a)
#pragma unroll
    for (int b = 0; b < 4; ++b) acc[a][b] = {0.f, 0.f, 0.f, 0.f};

  // B gather constants (coalesced over d1; transposing scatter, 0-conflict)
  const int c0 = t, c1 = t + 512;
  const int bn0 = c0 & 127, bkc0 = c0 >> 7; // d1 row, k-chunk (8 k's)
  const int bn1 = c1 & 127, bkc1 = c1 >> 7;

  float hhA[16], hhB[16];

#define LOADW(hh, Wb, h)                                                      \
  {                                                                           \
    _Pragma("unroll")                                                         \
    for (int j = 0; j < 8; ++j)                                               \
      hh[j] = (Wb)[(size_t)((h) * 64 + bkc0 * 8 + j) * 128 + bn0];            \
    _Pragma("unroll")                                                         \
    for (int j = 0; j < 8; ++j)                                               \
      hh[8 + j] = (Wb)[(size_t)((h) * 64 + bkc1 * 8 + j) * 128 + bn1];        \
  }

#define PACKB(Bb, hh)                                                         \
  {                                                                           \
    uint32_t p[8];                                                            \
    _Pragma("unroll")                                                         \
    for (int qq = 0; qq < 8; ++qq)                                            \
      p[qq] = (uint32_t)f2bf(hh[qq * 2]) | ((uint32_t)f2bf(hh[qq * 2 + 1]) << 16); \
    *reinterpret_cast<uint4*>((Bb) + ((bn0 * 128 + bkc0 * 16) ^ ((bn0 & 7) << 4))) = \
        make_uint4(p[0], p[1], p[2], p[3]);                                   \
    *reinterpret_cast<uint4*>((Bb) + ((bn1 * 128 + bkc1 * 16) ^ ((bn1 & 7) << 4))) = \
        make_uint4(p[4], p[5], p[6], p[7]);                                   \
  }

#define MFMA_HALF(h, Bb)                                                      \
  {                                                                           \
    _Pragma("unroll")                                                         \
    for (int kk = 0; kk < 64; kk += 32) {                                     \
      const int kb = kk + (lane >> 4) * 8;                                    \
      const int ka = (h) * 64 + kb;                                           \
      bf16x8 af[4], bfr[4];                                                   \
      _Pragma("unroll")                                                       \
      for (int mf = 0; mf < 4; ++mf) {                                        \
        int row = wm * 64 + mf * 16 + (lane & 15);                            \
        int byte = (row * 256 + ka * 2) ^ ((row & 7) << 4);                   \
        af[mf] = *reinterpret_cast<const bf16x8*>(Alds + byte);               \
      }                                                                       \
      _Pragma("unroll")                                                       \
      for (int nf = 0; nf < 4; ++nf) {                                        \
        int n = wn * 64 + nf * 16 + (lane & 15);                              \
        int byte = (n * 128 + kb * 2) ^ ((n & 7) << 4);                       \
        bfr[nf] = *reinterpret_cast<const bf16x8*>((Bb) + byte);              \
      }                                                                       \
      _Pragma("unroll")                                                       \
      for (int mf = 0; mf < 4; ++mf)                                          \
        _Pragma("unroll")                                                     \
        for (int nf = 0; nf < 4; ++nf)                                        \
          acc[mf][nf] = __builtin_amdgcn_mfma_f32_16x16x32_bf16(af[mf], bfr[nf], acc[mf][nf], 0, 0, 0); \
    }                                                                         \
  }

  // ---- prologue: A-DMA first (oldest vmem), then W(0), W(1).
  // In-order retirement => compiler's auto-wait for hhA implies A-DMA done.
#pragma unroll
  for (int s = 0; s < 8; ++s) {
    int seg = wave * 8 + s;                 // 64 segs x 1024B (4 rows of 256B)
    int row = seg * 4 + (lane >> 4);
    int srcc = (lane & 15) ^ (row & 7);     // source pre-swizzle (linear dest)
    gld_lds16(xb + (size_t)row * 8192 + srcc * 8, Alds + seg * 1024);
  }
  __builtin_amdgcn_sched_barrier(0);
  {
    const float* Wb = W + ((size_t)n1base * 64 + n0) * 16384;
    LOADW(hhA, Wb, 0);
    __builtin_amdgcn_sched_barrier(0);
    LOADW(hhB, Wb, 1);
    __builtin_amdgcn_sched_barrier(0);
  }

#pragma unroll 1
  for (int i = 0; i < 8; ++i) {
    const int n1 = n1base + i;
    const float* Wn = W + ((size_t)(n1 + 1) * 64 + n0) * 16384;  // next n1

    // step even: k-half 0 via B0/hhA
    PACKB(Bl0, hhA);
    if (i < 7) { LOADW(hhA, Wn, 0); }       // W(s+2), in flight across barriers
    __builtin_amdgcn_sched_barrier(0);
    bar_lgkm();
    MFMA_HALF(0, Bl0);

    // step odd: k-half 1 via B1/hhB
    PACKB(Bl1, hhB);
    if (i < 7) { LOADW(hhB, Wn, 1); }
    __builtin_amdgcn_sched_barrier(0);
    bar_lgkm();
    MFMA_HALF(1, Bl1);

    // epilogue n1: 2 rounds of 128 b-rows; region = Epi (lower 64) + stale Bl1
    // (upper 64; repacked only after next iter's first barrier). Stores are
    // fire-and-forget (no vmcnt wait -> don't stall W prefetch).
    ushort* ub = ubase + (size_t)n1 * 8192;
#pragma unroll
    for (int r = 0; r < 2; ++r) {
      bar_lgkm();                           // MFMA's B1-reads done before overwrite
      if ((wm >> 1) == r) {
        char* dst = (wm & 1) ? Bl1 : Epi;
#pragma unroll
        for (int mf = 0; mf < 4; ++mf) {
#pragma unroll
          for (int nf = 0; nf < 4; ++nf) {
            int col = wn * 64 + nf * 16 + (lane & 15);
#pragma unroll
            for (int j = 0; j < 4; ++j) {
              int rr = mf * 16 + (lane >> 4) * 4 + j;
              int byte = (rr * 256 + col * 2) ^ ((rr & 7) << 4);
              *reinterpret_cast<ushort*>(dst + byte) = f2bf(acc[mf][nf][j]);
            }
          }
        }
      }
      bar_lgkm();
#pragma unroll
      for (int ci = 0; ci < 4; ++ci) {
        int c = t + ci * 512;               // 2048 x 16B = 32KB
        int rowl = c >> 4;
        int cb = (c & 15) * 16;
        int rr = rowl & 63;
        const char* src = (rowl < 64) ? Epi : Bl1;
        int sbyte = (rr * 256 + cb) ^ ((rr & 7) << 4);
        uint4 v = *reinterpret_cast<const uint4*>(src + sbyte);
        int row = r * 128 + rowl;
        *reinterpret_cast<uint4*>(ub + (size_t)row * 524288 + cb / 2) = v;
      }
    }
    bar_lgkm();                             // copyout reads done before next packB
#pragma unroll
    for (int a = 0; a < 4; ++a)
#pragma unroll
      for (int b = 0; b < 4; ++b) acc[a][b] = {0.f, 0.f, 0.f, 0.f};
  }
#undef LOADW
#undef PACKB
#undef MFMA_HALF
}

// ---------------- K2: s = sum_n0 u ; logits = (u . s)/sqrt(128)
// Grid reversed: reads the u K1 wrote LAST first (still L3-resident), and
// leaves low-address u in L3 for K4's ascending pass.
__global__ __launch_bounds__(256) void k2_logits(
    const ushort* __restrict__ u, float* __restrict__ logits)
{
  const int bid = gridDim.x - 1 - blockIdx.x;  // b*64 + n1, reversed
  const ushort* up = u + (size_t)bid * 8192;   // [n0][d1] 64x128
  const int t = threadIdx.x;

  __shared__ float part[8][128];
  __shared__ float sS[128];
  __shared__ float part2[256];

  {
    int d4 = (t & 31) * 4;
    int g = t >> 5;                     // n0 group of 8
    float4 a = {0, 0, 0, 0};
    for (int n0 = g * 8; n0 < g * 8 + 8; ++n0) {
      ushort4 v = *reinterpret_cast<const ushort4*>(up + n0 * 128 + d4);
      a.x += bf2f(v.x); a.y += bf2f(v.y); a.z += bf2f(v.z); a.w += bf2f(v.w);
    }
    *reinterpret_cast<float4*>(&part[g][d4]) = a;
  }
  __syncthreads();
  if (t < 128) {
    float s = 0;
#pragma unroll
    for (int g = 0; g < 8; ++g) s += part[g][t];
    sS[t] = s;
  }
  __syncthreads();
  {
    int n0 = t >> 2, qq = t & 3;
    float acc = 0;
#pragma unroll
    for (int j = 0; j < 32; j += 4) {
      int d = qq * 32 + j;
      ushort4 v = *reinterpret_cast<const ushort4*>(up + n0 * 128 + d);
      acc += bf2f(v.x) * sS[d] + bf2f(v.y) * sS[d + 1] + bf2f(v.z) * sS[d + 2] + bf2f(v.w) * sS[d + 3];
    }
    part2[t] = acc;
  }
  __syncthreads();
  if (t < 64) {
    float l = (part2[t * 4] + part2[t * 4 + 1] + part2[t * 4 + 2] + part2[t * 4 + 3]) * 0.08838834764831845f;
    logits[(size_t)bid * 64 + t] = l;
  }
}

// ---------------- K3: softmax over n1 (per (b,n0)) + bias
__global__ __launch_bounds__(64) void k3_softmax(
    const float* __restrict__ logits, const float* __restrict__ bias,
    float* __restrict__ cc)
{
  const int b = blockIdx.x;
  const int t = threadIdx.x;            // = n0
  __shared__ float L[64][64];           // [n1][n0]
  const float* lp = logits + (size_t)b * 4096;
  for (int i = 0; i < 64; ++i) L[i][t] = lp[i * 64 + t];
  __syncthreads();
  float m = -1e30f;
#pragma unroll
  for (int n1 = 0; n1 < 64; ++n1) m = fmaxf(m, L[n1][t]);
  float sum = 0.f;
#pragma unroll
  for (int n1 = 0; n1 < 64; ++n1) {
    float e = __expf(L[n1][t] - m);
    L[n1][t] = e;
    sum += e;
  }
  float inv = 1.0f / sum;
  float* cp = cc + (size_t)b * 4096;
  for (int n1 = 0; n1 < 64; ++n1)
    cp[n1 * 64 + t] = L[n1][t] * inv + bias[n1 * 64 + t];
}

// ---------------- K4: out[b,n1,d1] = sum_n0 u * c
__global__ __launch_bounds__(128) void k4_out(
    const ushort* __restrict__ u, const float* __restrict__ cc,
    float* __restrict__ out)
{
  const int bid = blockIdx.x;           // b*64 + n1
  const ushort* up = u + (size_t)bid * 8192;
  const int t = threadIdx.x;
  __shared__ float cL[64];
  __shared__ float part[4][128];
  if (t < 64) cL[t] = cc[(size_t)bid * 64 + t];
  __syncthreads();
  int d4 = (t & 31) * 4, g = t >> 5;    // g: n0 group of 16
  float4 a = {0, 0, 0, 0};
  for (int n0 = g * 16; n0 < g * 16 + 16; ++n0) {
    ushort4 v = *reinterpret_cast<const ushort4*>(up + n0 * 128 + d4);
    float c = cL[n0];
    a.x += bf2f(v.x) * c; a.y += bf2f(v.y) * c; a.z += bf2f(v.z) * c; a.w += bf2f(v.w) * c;
  }
  *reinterpret_cast<float4*>(&part[g][d4]) = a;
  __syncthreads();
  if (t < 128) {
    float r = part[0][t] + part[1][t] + part[2][t] + part[3][t];
    out[(size_t)bid * 128 + t] = r;
  }
}

extern "C" void kernel_launch(void* const* d_in, const int* in_sizes, int n_in,
                              void* d_out, int out_size, void* d_ws, size_t ws_size,
                              hipStream_t stream) {
  const float* x = (const float*)d_in[0];
  const float* W = (const float*)d_in[1];
  const float* bias = (const float*)d_in[2];
  float* out = (float*)d_out;

  ushort* u = (ushort*)d_ws;                                   // 268435456 B
  float* logits = (float*)((char*)d_ws + 268435456u);          // 4194304 B
  char* ccxbf = (char*)d_ws + 272629760u;                      // 4194304 B shared
  ushort* xbf = (ushort*)ccxbf;     // live Px..K1
  float* cc = (float*)ccxbf;        // live K3..K4 (overwrites xbf after K1 done)

  hipLaunchKernelGGL(px_cvt,     dim3(1024),     dim3(512), 0, stream, x, xbf);
  hipLaunchKernelGGL(k1_gemm,    dim3(512),      dim3(512), 0, stream, xbf, W, u);
  hipLaunchKernelGGL(k2_logits,  dim3(BB * NN1), dim3(256), 0, stream, u, logits);
  hipLaunchKernelGGL(k3_softmax, dim3(BB),       dim3(64),  0, stream, logits, bias, cc);
  hipLaunchKernelGGL(k4_out,     dim3(BB * NN1), dim3(128), 0, stream, u, cc, out);
}

// Round 6
// 204.865 us; speedup vs baseline: 1.4658x; 1.4658x over previous
//
#include <hip/hip_runtime.h>
#include <hip/hip_bf16.h>
#include <cstdint>

// Problem: B=256, N0=64, D0=128, N1=64, D1=128 (all fp32 in/out).
// u[b,n1,n0,d1] = sum_d0 x[b,n0,d0]*W[n1,n0,d0,d1]
// s = sum_n0 u ; logit = (u . s)/sqrt(128) ; c = softmax_n1(logit) + bias
// out[b,n1,d1] = sum_n0 u*c
//
// ws layout: u bf16 [B][N1][N0][D1]      @ 0          (268435456 B)
//            logits f32 [B][N1][N0]      @ 268435456  (4194304 B)
//            cc/xbf shared region        @ 272629760  (4194304 B)
//
// REGISTER BUDGET RULE (R4/R5 lesson): unified VGPR+AGPR must stay <= ~128/wave
// or occupancy collapses to 8 waves/CU (192 regs -> 2 waves/SIMD, measured 22%).
// Hence wave-tile 64x32 (acc=32 AGPR) and single-chunk W gathers (hh=8+8).

#define BB 256
#define NN0 64
#define DD0 128
#define NN1 64
#define DD1 128

typedef __attribute__((ext_vector_type(8))) short bf16x8;
typedef __attribute__((ext_vector_type(4))) float f32x4;

__device__ __forceinline__ ushort f2bf(float f) {
  uint32_t b = __float_as_uint(f);
  b += 0x7FFFu + ((b >> 16) & 1u);      // RNE
  return (ushort)(b >> 16);
}
__device__ __forceinline__ float bf2f(ushort h) {
  return __uint_as_float(((uint32_t)h) << 16);
}

__device__ __forceinline__ void gld_lds16(const void* g, void* l) {
  __builtin_amdgcn_global_load_lds(
      (const __attribute__((address_space(1))) void*)g,
      (__attribute__((address_space(3))) void*)l, 16, 0, 0);
}

// barrier that does NOT drain vmcnt (W prefetch stays in flight across it).
__device__ __forceinline__ void bar_lgkm() {
  asm volatile("s_waitcnt lgkmcnt(0)" ::: "memory");
  __builtin_amdgcn_s_barrier();
  __builtin_amdgcn_sched_barrier(0);
}

// ---------------- Px: x fp32 -> bf16
__global__ __launch_bounds__(512) void px_cvt(
    const float* __restrict__ x, ushort* __restrict__ xbf)
{
  int i = blockIdx.x * 512 + threadIdx.x;   // 524288 float4 chunks total
  float4 v = *reinterpret_cast<const float4*>(x + (size_t)i * 4);
  ushort4 h;
  h.x = f2bf(v.x); h.y = f2bf(v.y); h.z = f2bf(v.z); h.w = f2bf(v.w);
  *reinterpret_cast<ushort4*>(xbf + (size_t)i * 4) = h;
}

// ---------------- K1: block = (n1, n0, b-half). M=128(b) x N=128(d1), K=128.
// A staged ONCE (full K) via global_load_lds; W streamed as 4 k-steps of 32
// through dbuf B-LDS; lgkm-only barriers keep W(k+1),W(k+2) in flight (T3/T4
// via the compiler's precise vmcnt waits). LDS: A 32K + B 8K*2 = 48KB.
__global__ __launch_bounds__(512, 2) void k1_gemm(
    const ushort* __restrict__ xbf, const float* __restrict__ W,
    ushort* __restrict__ u)
{
  __shared__ __align__(16) char lds[49152];
  char* Alds = lds;                          // 128 rows(b) x 256B (k=128), XOR-swz
  char* Bl[2] = { lds + 32768, lds + 40960 };// 128 rows(d1) x 64B (32 k), swz

  // XCD-chunk: 8192 blocks = 8 XCDs x 1024; XCD owns n0 in [x*8,x*8+8).
  const int q = blockIdx.x;
  const int local = (q >> 3) | ((q & 7) << 10);   // bijective (8192 = 8*1024)
  const int n0 = local >> 7;                       // (q&7)*8 + (local'>>7)
  const int n1 = (local >> 1) & 63;
  const int bh = local & 1;
  const int t = threadIdx.x;
  const int lane = t & 63, wave = t >> 6;
  const int wm = wave >> 2, wn = wave & 3;   // 2 M-waves(64b) x 4 N-waves(32 d1)

  const ushort* xb = xbf + n0 * DD0 + (size_t)bh * 128 * 8192;  // + row*8192 + d0
  const float* Wb = W + ((size_t)n1 * NN0 + n0) * (DD0 * DD1);  // [d0][d1]
  ushort* ub = u + ((size_t)n1 * 8192 + (size_t)n0 * 128 + (size_t)bh * 128 * 524288);

  f32x4 acc[4][2];
#pragma unroll
  for (int a = 0; a < 4; ++a)
#pragma unroll
    for (int b = 0; b < 2; ++b) acc[a][b] = {0.f, 0.f, 0.f, 0.f};

  // W gather: one chunk per thread: d1 = t&127, kc = t>>7 (8 consecutive k's)
  const int gd1 = t & 127, gkc = t >> 7;
  const int bbyte = (gd1 * 64 + gkc * 16) ^ ((gd1 & 3) << 4) ^ (((gd1 >> 2) & 1) << 6);
  float hhA[8], hhB[8];

#define LOADW(hh, ks)                                                         \
  {                                                                           \
    _Pragma("unroll")                                                         \
    for (int j = 0; j < 8; ++j)                                               \
      hh[j] = Wb[(size_t)((ks) * 32 + gkc * 8 + j) * 128 + gd1];              \
  }
#define PACKB(bi, hh)                                                         \
  {                                                                           \
    uint32_t p0 = (uint32_t)f2bf(hh[0]) | ((uint32_t)f2bf(hh[1]) << 16);      \
    uint32_t p1 = (uint32_t)f2bf(hh[2]) | ((uint32_t)f2bf(hh[3]) << 16);      \
    uint32_t p2 = (uint32_t)f2bf(hh[4]) | ((uint32_t)f2bf(hh[5]) << 16);      \
    uint32_t p3 = (uint32_t)f2bf(hh[6]) | ((uint32_t)f2bf(hh[7]) << 16);      \
    *reinterpret_cast<uint4*>(Bl[bi] + bbyte) = make_uint4(p0, p1, p2, p3);   \
  }
#define MFMA_STEP(ks, bi)                                                     \
  {                                                                           \
    const int kb16 = (lane >> 4);                                             \
    const int ka = (ks) * 32 + kb16 * 8;                                      \
    bf16x8 af[4], bfr[2];                                                     \
    _Pragma("unroll")                                                         \
    for (int mf = 0; mf < 4; ++mf) {                                          \
      int row = wm * 64 + mf * 16 + (lane & 15);                              \
      int byte = (row * 256 + ka * 2) ^ ((row & 7) << 4);                     \
      af[mf] = *reinterpret_cast<const bf16x8*>(Alds + byte);                 \
    }                                                                         \
    _Pragma("unroll")                                                         \
    for (int nf = 0; nf < 2; ++nf) {                                          \
      int n = wn * 32 + nf * 16 + (lane & 15);                                \
      int byte = (n * 64 + kb16 * 16) ^ ((n & 3) << 4) ^ (((n >> 2) & 1) << 6); \
      bfr[nf] = *reinterpret_cast<const bf16x8*>(Bl[bi] + byte);              \
    }                                                                         \
    _Pragma("unroll")                                                         \
    for (int mf = 0; mf < 4; ++mf)                                            \
      _Pragma("unroll")                                                       \
      for (int nf = 0; nf < 2; ++nf)                                          \
        acc[mf][nf] = __builtin_amdgcn_mfma_f32_16x16x32_bf16(af[mf], bfr[nf], acc[mf][nf], 0, 0, 0); \
  }

  // ---- prologue. Issue order matters: A-DMA oldest, then W0, W1.
  // pack0's compiler wait (vmcnt leaves W1+W2 in flight) implies A-DMA done.
#pragma unroll
  for (int s = 0; s < 4; ++s) {
    int seg = wave * 4 + s;                  // 32 segs x 1024B (4 rows of 256B)
    int row = seg * 4 + (lane >> 4);
    int srcc = (lane & 15) ^ (row & 7);      // source pre-swizzle (linear dest)
    gld_lds16(xb + (size_t)row * 8192 + srcc * 8, Alds + seg * 1024);
  }
  __builtin_amdgcn_sched_barrier(0);
  LOADW(hhA, 0);
  __builtin_amdgcn_sched_barrier(0);
  LOADW(hhB, 1);
  __builtin_amdgcn_sched_barrier(0);
  PACKB(0, hhA);                             // waits W0 (and A, older); W1 flies
  LOADW(hhA, 2);                             // W2 in flight across barrier
  __builtin_amdgcn_sched_barrier(0);
  bar_lgkm();

  // ---- 4 k-steps; pack(k+1) before MFMA(k) (different buffer, no bar needed);
  // one lgkm-barrier per step.
  PACKB(1, hhB);                             // waits W1; W2 flies
  LOADW(hhB, 3);                             // W3 in flight
  __builtin_amdgcn_sched_barrier(0);
  MFMA_STEP(0, 0);
  bar_lgkm();

  PACKB(0, hhA);                             // waits W2; W3 flies
  __builtin_amdgcn_sched_barrier(0);
  MFMA_STEP(1, 1);
  bar_lgkm();

  PACKB(1, hhB);                             // waits W3
  __builtin_amdgcn_sched_barrier(0);
  MFMA_STEP(2, 0);
  bar_lgkm();

  MFMA_STEP(3, 1);

  // ---- epilogue: stage u rows through A-region (32KB = 128 rows x 256B)
  bar_lgkm();                                // all MFMA ds_reads of A done
#pragma unroll
  for (int mf = 0; mf < 4; ++mf) {
#pragma unroll
    for (int nf = 0; nf < 2; ++nf) {
      int col = wn * 32 + nf * 16 + (lane & 15);
#pragma unroll
      for (int j = 0; j < 4; ++j) {
        int rr = wm * 64 + mf * 16 + (lane >> 4) * 4 + j;
        int byte = (rr * 256 + col * 2) ^ ((rr & 7) << 4);
        *reinterpret_cast<ushort*>(Alds + byte) = f2bf(acc[mf][nf][j]);
      }
    }
  }
  bar_lgkm();
#pragma unroll
  for (int ci = 0; ci < 4; ++ci) {
    int c = t + ci * 512;                    // 2048 x 16B chunks = 32KB
    int rowl = c >> 4;
    int cb = (c & 15) * 16;
    int sbyte = (rowl * 256 + cb) ^ ((rowl & 7) << 4);
    uint4 v = *reinterpret_cast<uint4*>(Alds + sbyte);
    *reinterpret_cast<uint4*>(ub + (size_t)rowl * 524288 + cb / 2) = v;
  }
#undef LOADW
#undef PACKB
#undef MFMA_STEP
}

// ---------------- K2: s = sum_n0 u ; logits = (u . s)/sqrt(128)
// Grid reversed: reads the u K1 wrote last first (L3-resident).
__global__ __launch_bounds__(256) void k2_logits(
    const ushort* __restrict__ u, float* __restrict__ logits)
{
  const int bid = gridDim.x - 1 - blockIdx.x;  // b*64 + n1, reversed
  const ushort* up = u + (size_t)bid * 8192;   // [n0][d1] 64x128
  const int t = threadIdx.x;

  __shared__ float part[8][128];
  __shared__ float sS[128];
  __shared__ float part2[256];

  {
    int d4 = (t & 31) * 4;
    int g = t >> 5;                     // n0 group of 8
    float4 a = {0, 0, 0, 0};
    for (int n0 = g * 8; n0 < g * 8 + 8; ++n0) {
      ushort4 v = *reinterpret_cast<const ushort4*>(up + n0 * 128 + d4);
      a.x += bf2f(v.x); a.y += bf2f(v.y); a.z += bf2f(v.z); a.w += bf2f(v.w);
    }
    *reinterpret_cast<float4*>(&part[g][d4]) = a;
  }
  __syncthreads();
  if (t < 128) {
    float s = 0;
#pragma unroll
    for (int g = 0; g < 8; ++g) s += part[g][t];
    sS[t] = s;
  }
  __syncthreads();
  {
    int n0 = t >> 2, qq = t & 3;
    float acc = 0;
#pragma unroll
    for (int j = 0; j < 32; j += 4) {
      int d = qq * 32 + j;
      ushort4 v = *reinterpret_cast<const ushort4*>(up + n0 * 128 + d);
      acc += bf2f(v.x) * sS[d] + bf2f(v.y) * sS[d + 1] + bf2f(v.z) * sS[d + 2] + bf2f(v.w) * sS[d + 3];
    }
    part2[t] = acc;
  }
  __syncthreads();
  if (t < 64) {
    float l = (part2[t * 4] + part2[t * 4 + 1] + part2[t * 4 + 2] + part2[t * 4 + 3]) * 0.08838834764831845f;
    logits[(size_t)bid * 64 + t] = l;
  }
}

// ---------------- K3: softmax over n1 (per (b,n0)) + bias
__global__ __launch_bounds__(64) void k3_softmax(
    const float* __restrict__ logits, const float* __restrict__ bias,
    float* __restrict__ cc)
{
  const int b = blockIdx.x;
  const int t = threadIdx.x;            // = n0
  __shared__ float L[64][64];           // [n1][n0]
  const float* lp = logits + (size_t)b * 4096;
  for (int i = 0; i < 64; ++i) L[i][t] = lp[i * 64 + t];
  __syncthreads();
  float m = -1e30f;
#pragma unroll
  for (int n1 = 0; n1 < 64; ++n1) m = fmaxf(m, L[n1][t]);
  float sum = 0.f;
#pragma unroll
  for (int n1 = 0; n1 < 64; ++n1) {
    float e = __expf(L[n1][t] - m);
    L[n1][t] = e;
    sum += e;
  }
  float inv = 1.0f / sum;
  float* cp = cc + (size_t)b * 4096;
  for (int n1 = 0; n1 < 64; ++n1)
    cp[n1 * 64 + t] = L[n1][t] * inv + bias[n1 * 64 + t];
}

// ---------------- K4: out[b,n1,d1] = sum_n0 u * c
__global__ __launch_bounds__(128) void k4_out(
    const ushort* __restrict__ u, const float* __restrict__ cc,
    float* __restrict__ out)
{
  const int bid = blockIdx.x;           // b*64 + n1
  const ushort* up = u + (size_t)bid * 8192;
  const int t = threadIdx.x;
  __shared__ float cL[64];
  __shared__ float part[4][128];
  if (t < 64) cL[t] = cc[(size_t)bid * 64 + t];
  __syncthreads();
  int d4 = (t & 31) * 4, g = t >> 5;    // g: n0 group of 16
  float4 a = {0, 0, 0, 0};
  for (int n0 = g * 16; n0 < g * 16 + 16; ++n0) {
    ushort4 v = *reinterpret_cast<const ushort4*>(up + n0 * 128 + d4);
    float c = cL[n0];
    a.x += bf2f(v.x) * c; a.y += bf2f(v.y) * c; a.z += bf2f(v.z) * c; a.w += bf2f(v.w) * c;
  }
  *reinterpret_cast<float4*>(&part[g][d4]) = a;
  __syncthreads();
  if (t < 128) {
    float r = part[0][t] + part[1][t] + part[2][t] + part[3][t];
    out[(size_t)bid * 128 + t] = r;
  }
}

extern "C" void kernel_launch(void* const* d_in, const int* in_sizes, int n_in,
                              void* d_out, int out_size, void* d_ws, size_t ws_size,
                              hipStream_t stream) {
  const float* x = (const float*)d_in[0];
  const float* W = (const float*)d_in[1];
  const float* bias = (const float*)d_in[2];
  float* out = (float*)d_out;

  ushort* u = (ushort*)d_ws;                                   // 268435456 B
  float* logits = (float*)((char*)d_ws + 268435456u);          // 4194304 B
  char* ccxbf = (char*)d_ws + 272629760u;                      // 4194304 B shared
  ushort* xbf = (ushort*)ccxbf;     // live Px..K1
  float* cc = (float*)ccxbf;        // live K3..K4 (overwrites xbf after K1 done)

  hipLaunchKernelGGL(px_cvt,     dim3(1024),     dim3(512), 0, stream, x, xbf);
  hipLaunchKernelGGL(k1_gemm,    dim3(8192),     dim3(512), 0, stream, xbf, W, u);
  hipLaunchKernelGGL(k2_logits,  dim3(BB * NN1), dim3(256), 0, stream, u, logits);
  hipLaunchKernelGGL(k3_softmax, dim3(BB),       dim3(64),  0, stream, logits, bias, cc);
  hipLaunchKernelGGL(k4_out,     dim3(BB * NN1), dim3(128), 0, stream, u, cc, out);
}